// Round 2
// baseline (443.035 us; speedup 1.0000x reference)
//
#include <hip/hip_runtime.h>

// 3D RoPE for WanS2V: x (1, 32760, 16, 128) fp32, interleaved complex pairs.
// s = f*h*w = 21*30*52 = 32760. Half-channels: [0,22) use f-index row,
// [22,43) use h-index row, [43,64) use w-index row of the 1024x64 cos/sin tables.
// Memory-bound: 268.4 MB in + 268.4 MB out; tables (512 KB) stay L2-hot.
// Roofline: 537 MB / 6.3 TB/s ~= 85 us.

#define F_DIM   22
#define H_DIM   21
#define C_HALF  64          // F_DIM + H_DIM + W_DIM
#define F_N     21
#define H_N     30
#define W_N     52
#define HW_N    (H_N * W_N) // 1560
#define N_HEADS 16
#define D_DIM   128
#define S_TOT   (F_N * HW_N)            // 32760
#define N_FLOAT4 (S_TOT * N_HEADS * (D_DIM / 4))  // 16,773,120

// grid chosen so stride is a multiple of 512 -> d4/c0/c1 loop-invariant
#define NBLOCKS 2048
#define NTHREADS 256

__global__ __launch_bounds__(NTHREADS) void rope3d_kernel(
    const float4* __restrict__ x,
    const float*  __restrict__ cos_tab,
    const float*  __restrict__ sin_tab,
    float4*       __restrict__ out)
{
    const int stride = NBLOCKS * NTHREADS;          // 524288, multiple of 512
    const int i0 = blockIdx.x * NTHREADS + threadIdx.x;

    // Loop-invariant per thread (stride % 512 == 0):
    const int d4 = i0 & 31;         // float4 index within d-row: 0..31
    const int c0 = d4 * 2;          // half-channel of (v.x, v.y)
    const int c1 = c0 + 1;          // half-channel of (v.z, v.w)
    // which spatial axis each half-channel uses: 0=f, 1=h, 2=w
    const int sel0 = (c0 < F_DIM) ? 0 : (c0 < F_DIM + H_DIM) ? 1 : 2;
    const int sel1 = (c1 < F_DIM) ? 0 : (c1 < F_DIM + H_DIM) ? 1 : 2;

    for (int i = i0; i < N_FLOAT4; i += stride) {
        const int s  = i >> 9;      // / (32 float4 * 16 heads)

        // s -> (fi, hi, wi); compile-time divisors -> magic mul
        const int fi  = s / HW_N;
        const int rem = s - fi * HW_N;
        const int hi  = rem / W_N;
        const int wi  = rem - hi * W_N;

        const int row0 = (sel0 == 0) ? fi : (sel0 == 1) ? hi : wi;
        const int row1 = (sel1 == 0) ? fi : (sel1 == 1) ? hi : wi;

        const float cs0 = cos_tab[row0 * C_HALF + c0];
        const float sn0 = sin_tab[row0 * C_HALF + c0];
        const float cs1 = cos_tab[row1 * C_HALF + c1];
        const float sn1 = sin_tab[row1 * C_HALF + c1];

        const float4 v = x[i];
        float4 o;
        o.x = v.x * cs0 - v.y * sn0;
        o.y = v.x * sn0 + v.y * cs0;
        o.z = v.z * cs1 - v.w * sn1;
        o.w = v.z * sn1 + v.w * cs1;
        out[i] = o;
    }
}

extern "C" void kernel_launch(void* const* d_in, const int* in_sizes, int n_in,
                              void* d_out, int out_size, void* d_ws, size_t ws_size,
                              hipStream_t stream) {
    const float4* x       = (const float4*)d_in[0];
    const float*  cos_tab = (const float*)d_in[1];
    const float*  sin_tab = (const float*)d_in[2];
    float4*       out     = (float4*)d_out;

    // 2048 blocks x 256 threads = full co-residency on 256 CUs;
    // grid-stride covers the 16.8M float4 elements (32 iters/thread).
    rope3d_kernel<<<NBLOCKS, NTHREADS, 0, stream>>>(x, cos_tab, sin_tab, out);
}

// Round 4
// 438.955 us; speedup vs baseline: 1.0093x; 1.0093x over previous
//
#include <hip/hip_runtime.h>

// 3D RoPE for WanS2V: x (1, 32760, 16, 128) fp32, interleaved complex pairs.
// s = f*h*w = 21*30*52 = 32760. Half-channels: [0,22) use f-row, [22,43) h-row,
// [43,64) w-row of the 1024x64 cos/sin tables (512 KB total, L2-resident).
// Memory-bound: 268.4 MB in + 268.4 MB out -> floor ~85 us at 6.3 TB/s.
//
// Structure: exact-trip-count unrolled loop (no grid-stride bound check) so the
// compiler keeps 8 independent 16B loads in flight per thread. Thread stride
// (2,096,640) is a multiple of 512 -> per-thread d4/c0/c1/sel are loop-invariant
// and s advances by exactly 4095 per iteration. Non-temporal load/store on the
// streamed x/out (clang ext_vector type: the builtin rejects HIP_vector_type).

typedef float f32x4 __attribute__((ext_vector_type(4)));

#define F_DIM   22
#define FH_DIM  43          // F_DIM + H_DIM
#define C_HALF  64
#define HW_N    1560        // 30*52
#define W_N     52
#define N_FLOAT4 16773120   // 32760 * 16 * 32

#define NTHREADS 256
#define NBLOCKS  8190
#define T_TOTAL  (NBLOCKS * NTHREADS)   // 2,096,640 = 512 * 4095
#define S_STEP   4095                   // T_TOTAL / 512
#define K_ITERS  8                      // N_FLOAT4 / T_TOTAL exactly

__global__ __launch_bounds__(NTHREADS) void rope3d_kernel(
    const f32x4* __restrict__ x,
    const float* __restrict__ cos_tab,
    const float* __restrict__ sin_tab,
    f32x4*       __restrict__ out)
{
    const int i0 = blockIdx.x * NTHREADS + threadIdx.x;

    // loop-invariant per thread:
    const int d4 = i0 & 31;         // float4 index within d-row
    const int c0 = d4 * 2;
    const int c1 = c0 + 1;
    const int sel0 = (c0 < F_DIM) ? 0 : (c0 < FH_DIM) ? 1 : 2;
    const int sel1 = (c1 < F_DIM) ? 0 : (c1 < FH_DIM) ? 1 : 2;

    int s = i0 >> 9;                // spatial index; += S_STEP per iteration

#pragma unroll
    for (int k = 0; k < K_ITERS; ++k) {
        const int i = i0 + k * T_TOTAL;

        // s -> (fi, hi, wi); compile-time divisors -> magic mul
        const int fi  = s / HW_N;
        const int rem = s - fi * HW_N;
        const int hi  = rem / W_N;
        const int wi  = rem - hi * W_N;

        const int row0 = (sel0 == 0) ? fi : (sel0 == 1) ? hi : wi;
        const int row1 = (sel1 == 0) ? fi : (sel1 == 1) ? hi : wi;

        const float cs0 = cos_tab[row0 * C_HALF + c0];
        const float sn0 = sin_tab[row0 * C_HALF + c0];
        const float cs1 = cos_tab[row1 * C_HALF + c1];
        const float sn1 = sin_tab[row1 * C_HALF + c1];

        const f32x4 v = __builtin_nontemporal_load(&x[i]);
        f32x4 o;
        o.x = v.x * cs0 - v.y * sn0;
        o.y = v.x * sn0 + v.y * cs0;
        o.z = v.z * cs1 - v.w * sn1;
        o.w = v.z * sn1 + v.w * cs1;
        __builtin_nontemporal_store(o, &out[i]);

        s += S_STEP;
    }
}

extern "C" void kernel_launch(void* const* d_in, const int* in_sizes, int n_in,
                              void* d_out, int out_size, void* d_ws, size_t ws_size,
                              hipStream_t stream) {
    const f32x4* x       = (const f32x4*)d_in[0];
    const float* cos_tab = (const float*)d_in[1];
    const float* sin_tab = (const float*)d_in[2];
    f32x4*       out     = (f32x4*)d_out;

    rope3d_kernel<<<NBLOCKS, NTHREADS, 0, stream>>>(x, cos_tab, sin_tab, out);
}